// Round 4
// baseline (465.840 us; speedup 1.0000x reference)
//
#include <hip/hip_runtime.h>
#include <math.h>

#define NN 100000
#define EE 1600000
#define GG 64
#define NCLS 10

#define BSH 8                 // bucket = dst >> 8 (256 nodes per bucket)
#define NB 391                // ceil(NN / 256)
#define BCAP 4608             // fixed bucket capacity (mean 4092, sigma 64 -> 8 sigma)
#define EPS 4096              // edges per block in bscatter
#define CAPS 5120             // bsort LDS staging capacity (ints)
#define SBLK 391              // ceil(EE / EPS) bscatter blocks
#define GB 1563               // ceil(NN / 64) gemm/layer blocks

typedef unsigned int uint32;

__device__ __forceinline__ unsigned short f2bf(float f) {
    unsigned u = __float_as_uint(f);
    unsigned r = (u + 0x7fffu + ((u >> 16) & 1u)) >> 16;   // RNE
    return (unsigned short)r;
}

// ---------------- per-node GAT aggregation (R0-proven lane structure) ----------------
// lane owns (node d, head); accumulates all in-edges, applies softmax-normalize,
// bias + ELU, writes 8 f32 feats to out8 (LDS row segment).

__device__ __forceinline__ void agg_node(
    const uint4* __restrict__ Hq, const float* __restrict__ ALs,
    const float* __restrict__ ALd, const int2* __restrict__ rpe,
    const int* __restrict__ col, const float* __restrict__ bias,
    int d, int head, float* __restrict__ out8) {
    float ad = ALd[d * 8 + head];
    float acc0 = 0.f, acc1 = 0.f, acc2 = 0.f, acc3 = 0.f;
    float acc4 = 0.f, acc5 = 0.f, acc6 = 0.f, acc7 = 0.f;
    float wsum = 0.f;

#define FMA8(U, W) { \
    acc0 = fmaf(W, __uint_as_float((U).x << 16), acc0); \
    acc1 = fmaf(W, __uint_as_float((U).x & 0xffff0000u), acc1); \
    acc2 = fmaf(W, __uint_as_float((U).y << 16), acc2); \
    acc3 = fmaf(W, __uint_as_float((U).y & 0xffff0000u), acc3); \
    acc4 = fmaf(W, __uint_as_float((U).z << 16), acc4); \
    acc5 = fmaf(W, __uint_as_float((U).z & 0xffff0000u), acc5); \
    acc6 = fmaf(W, __uint_as_float((U).w << 16), acc6); \
    acc7 = fmaf(W, __uint_as_float((U).w & 0xffff0000u), acc7); }

    {   // self loop
        uint4 u = Hq[(size_t)d * 8 + head];
        float e = ALs[d * 8 + head] + ad;
        e = fmaxf(e, 0.2f * e);
        float w = __expf(e);
        FMA8(u, w);
        wsum = w;
    }

    int2 kk = rpe[d];
    int k = kk.x, kend = kk.y;
    for (; k + 4 <= kend; k += 4) {
        int s0 = col[k], s1 = col[k + 1], s2 = col[k + 2], s3 = col[k + 3];
        uint4 u0 = Hq[(size_t)s0 * 8 + head];
        uint4 u1 = Hq[(size_t)s1 * 8 + head];
        uint4 u2 = Hq[(size_t)s2 * 8 + head];
        uint4 u3 = Hq[(size_t)s3 * 8 + head];
        float a0 = ALs[s0 * 8 + head];
        float a1 = ALs[s1 * 8 + head];
        float a2 = ALs[s2 * 8 + head];
        float a3 = ALs[s3 * 8 + head];
        float e0 = a0 + ad; e0 = fmaxf(e0, 0.2f * e0); float w0 = __expf(e0);
        float e1 = a1 + ad; e1 = fmaxf(e1, 0.2f * e1); float w1 = __expf(e1);
        float e2 = a2 + ad; e2 = fmaxf(e2, 0.2f * e2); float w2 = __expf(e2);
        float e3 = a3 + ad; e3 = fmaxf(e3, 0.2f * e3); float w3 = __expf(e3);
        FMA8(u0, w0);
        FMA8(u1, w1);
        FMA8(u2, w2);
        FMA8(u3, w3);
        wsum += (w0 + w1) + (w2 + w3);
    }
    if (k + 2 <= kend) {
        int s0 = col[k], s1 = col[k + 1];
        uint4 u0 = Hq[(size_t)s0 * 8 + head];
        uint4 u1 = Hq[(size_t)s1 * 8 + head];
        float a0 = ALs[s0 * 8 + head];
        float a1 = ALs[s1 * 8 + head];
        float e0 = a0 + ad; e0 = fmaxf(e0, 0.2f * e0); float w0 = __expf(e0);
        float e1 = a1 + ad; e1 = fmaxf(e1, 0.2f * e1); float w1 = __expf(e1);
        FMA8(u0, w0);
        FMA8(u1, w1);
        wsum += w0 + w1;
        k += 2;
    }
    if (k < kend) {
        int s = col[k];
        uint4 u = Hq[(size_t)s * 8 + head];
        float a = ALs[s * 8 + head];
        float e = a + ad; e = fmaxf(e, 0.2f * e);
        float w = __expf(e);
        FMA8(u, w);
        wsum += w;
    }
#undef FMA8

    float inv = 1.f / wsum;
    float4 b0 = ((const float4*)bias)[head * 2];
    float4 b1 = ((const float4*)bias)[head * 2 + 1];
    float4 o0, o1;
    o0.x = fmaf(acc0, inv, b0.x); o0.x = o0.x > 0.f ? o0.x : expm1f(o0.x);
    o0.y = fmaf(acc1, inv, b0.y); o0.y = o0.y > 0.f ? o0.y : expm1f(o0.y);
    o0.z = fmaf(acc2, inv, b0.z); o0.z = o0.z > 0.f ? o0.z : expm1f(o0.z);
    o0.w = fmaf(acc3, inv, b0.w); o0.w = o0.w > 0.f ? o0.w : expm1f(o0.w);
    o1.x = fmaf(acc4, inv, b1.x); o1.x = o1.x > 0.f ? o1.x : expm1f(o1.x);
    o1.y = fmaf(acc5, inv, b1.y); o1.y = o1.y > 0.f ? o1.y : expm1f(o1.y);
    o1.z = fmaf(acc6, inv, b1.z); o1.z = o1.z > 0.f ? o1.z : expm1f(o1.z);
    o1.w = fmaf(acc7, inv, b1.w); o1.w = o1.w > 0.f ? o1.w : expm1f(o1.w);
    ((float4*)out8)[0] = o0;
    ((float4*)out8)[1] = o1;
}

// ---------------- node 2: bscatter (blocks < SBLK) || gemm1 K=128 (blocks >= SBLK) --------

__global__ __launch_bounds__(512) void pre_kernel(
    const int* __restrict__ src, const int* __restrict__ dst,
    int* __restrict__ bfill, uint32* __restrict__ bpack, int nE,
    const float* __restrict__ X, const float* __restrict__ W,
    const float* __restrict__ a_src, const float* __restrict__ a_dst,
    unsigned short* __restrict__ H, float* __restrict__ ALs, float* __restrict__ ALd) {
    __shared__ __align__(16) char smem[50176];
    int tid = threadIdx.x;

    if (blockIdx.x < SBLK) {
        // ---- bscatter role (512 threads) ----
        int* hist  = (int*)smem;
        int* gbase = hist + 512;
        int* lbase = gbase + 512;
        int* cnt2  = lbase + 512;
        int* wtot  = cnt2 + 512;            // 8
        uint32* lsd = (uint32*)(wtot + 8);  // EPS
        unsigned short* bkt = (unsigned short*)(lsd + EPS);  // EPS shorts

        int lane = tid & 63, wv = tid >> 6;
        int e0 = blockIdx.x * EPS;
        int e1 = min(e0 + EPS, nE);

        hist[tid] = 0;
        cnt2[tid] = 0;
        __syncthreads();
        for (int e = e0 + tid; e < e1; e += 512) atomicAdd(&hist[dst[e] >> BSH], 1);
        __syncthreads();
        int h = hist[tid];
        int inc = h;
#pragma unroll
        for (int off = 1; off < 64; off <<= 1) {
            int t = __shfl_up(inc, off);
            if (lane >= off) inc += t;
        }
        if (lane == 63) wtot[wv] = inc;
        __syncthreads();
        if (tid < 8) {
            int t = wtot[tid];
#pragma unroll
            for (int off = 1; off < 8; off <<= 1) {
                int u = __shfl_up(t, off, 8);
                if (tid >= off) t += u;
            }
            wtot[tid] = t;
        }
        __syncthreads();
        if (wv > 0) inc += wtot[wv - 1];
        int lb = inc - h;
        lbase[tid] = lb;
        int go = h > 0 ? atomicAdd(&bfill[tid], h) : 0;
        gbase[tid] = tid * BCAP + go - lb;   // g = gbase[b] + slot
        __syncthreads();
        for (int e = e0 + tid; e < e1; e += 512) {
            int s = src[e], dd = dst[e];
            int b = dd >> BSH;
            int r = atomicAdd(&cnt2[b], 1);
            int slot = lbase[b] + r;
            lsd[slot] = ((uint32)s << 8) | (uint32)(dd & 255);
            bkt[slot] = (unsigned short)b;
        }
        __syncthreads();
        int m = e1 - e0;
        for (int i = tid; i < m; i += 512)
            bpack[gbase[bkt[i]] + i] = lsd[i];
    } else {
        // ---- gemm1 role: 64x64 tile, K=128, 512 threads (2 rows x 4 cols each) ----
        const int K = 128, KC = 64, KP = 68;
        float* Xs = (float*)smem;            // 64*68
        float* Ws = Xs + 64 * KP;            // 128*64
        int r0 = (blockIdx.x - SBLK) * 64;
        int validRows = min(64, NN - r0);

        {
            const float4* Wg = (const float4*)W;
            float4* Ws4 = (float4*)Ws;
            for (int i = tid; i < K * 16; i += 512) Ws4[i] = Wg[i];
        }

        int cg = tid & 15, rg = tid >> 4;    // rg 0..31
        int rbase = rg * 2;
        float4 acc0 = make_float4(0.f, 0.f, 0.f, 0.f);
        float4 acc1 = acc0;

        const float4* Xg = (const float4*)X;
        const int QG = K / 4;

        for (int kc = 0; kc < K; kc += KC) {
            __syncthreads();
            for (int i = tid; i < 64 * 16; i += 512) {
                int row = i >> 4, q = i & 15;
                float4 v = (row < validRows)
                    ? Xg[(size_t)(r0 + row) * QG + (kc >> 2) + q]
                    : make_float4(0.f, 0.f, 0.f, 0.f);
                *(float4*)&Xs[row * KP + q * 4] = v;
            }
            __syncthreads();

#pragma unroll 2
            for (int k = 0; k < KC; k += 4) {
                float4 x0 = *(const float4*)&Xs[(rbase + 0) * KP + k];
                float4 x1 = *(const float4*)&Xs[(rbase + 1) * KP + k];
                float4 w0 = *(const float4*)&Ws[(kc + k + 0) * 64 + 4 * cg];
                float4 w1 = *(const float4*)&Ws[(kc + k + 1) * 64 + 4 * cg];
                float4 w2 = *(const float4*)&Ws[(kc + k + 2) * 64 + 4 * cg];
                float4 w3 = *(const float4*)&Ws[(kc + k + 3) * 64 + 4 * cg];
#define FMA4(A, S, WV) \
                A.x = fmaf(S, WV.x, A.x); A.y = fmaf(S, WV.y, A.y); \
                A.z = fmaf(S, WV.z, A.z); A.w = fmaf(S, WV.w, A.w)
                FMA4(acc0, x0.x, w0); FMA4(acc1, x1.x, w0);
                FMA4(acc0, x0.y, w1); FMA4(acc1, x1.y, w1);
                FMA4(acc0, x0.z, w2); FMA4(acc1, x1.z, w2);
                FMA4(acc0, x0.w, w3); FMA4(acc1, x1.w, w3);
#undef FMA4
            }
        }

        int hh = cg >> 1;
        float4 as4 = ((const float4*)a_src)[cg];
        float4 ad4 = ((const float4*)a_dst)[cg];
        float4 accs[2] = {acc0, acc1};
#pragma unroll
        for (int i = 0; i < 2; ++i) {
            int r = r0 + rbase + i;
            if (r < NN) {
                ushort4 p;
                p.x = f2bf(accs[i].x); p.y = f2bf(accs[i].y);
                p.z = f2bf(accs[i].z); p.w = f2bf(accs[i].w);
                ((ushort4*)H)[(size_t)r * 16 + cg] = p;
                float ps = accs[i].x * as4.x + accs[i].y * as4.y +
                           accs[i].z * as4.z + accs[i].w * as4.w;
                float pd = accs[i].x * ad4.x + accs[i].y * ad4.y +
                           accs[i].z * ad4.z + accs[i].w * ad4.w;
                ps += __shfl_xor(ps, 1);
                pd += __shfl_xor(pd, 1);
                if ((cg & 1) == 0) {
                    ALs[r * 8 + hh] = ps;
                    ALd[r * 8 + hh] = pd;
                }
            }
        }
    }
}

// ---------------- node 3: per-bucket counting sort -> rpe/col ----------------

__global__ __launch_bounds__(256) void bsort_kernel(
    const uint32* __restrict__ bpack, const int* __restrict__ bfill,
    int2* __restrict__ rpe, int* __restrict__ col) {
    __shared__ int cnt[256], cnt2[256];
    __shared__ int wtot[4];
    __shared__ int stage[CAPS];
    int b = blockIdx.x;
    int tid = threadIdx.x;
    int ebeg = b * BCAP;
    int sz = bfill[b];
    int n0 = b << BSH;
    int nn = min(256, NN - n0);

    cnt[tid] = 0;
    cnt2[tid] = 0;
    __syncthreads();
    const uint4* bq = (const uint4*)(bpack + ebeg);
    int nq = sz >> 2;
    for (int i = tid; i < nq; i += 256) {
        uint4 p = bq[i];
        atomicAdd(&cnt[p.x & 255u], 1);
        atomicAdd(&cnt[p.y & 255u], 1);
        atomicAdd(&cnt[p.z & 255u], 1);
        atomicAdd(&cnt[p.w & 255u], 1);
    }
    for (int e = (nq << 2) + tid; e < sz; e += 256)
        atomicAdd(&cnt[bpack[ebeg + e] & 255u], 1);
    __syncthreads();
    int lane = tid & 63, wv = tid >> 6;
    int c = cnt[tid];
    int inc = c;
#pragma unroll
    for (int off = 1; off < 64; off <<= 1) {
        int t = __shfl_up(inc, off);
        if (lane >= off) inc += t;
    }
    if (lane == 63) wtot[wv] = inc;
    __syncthreads();
    if (tid < 4) {
        int t = wtot[tid];
#pragma unroll
        for (int off = 1; off < 4; off <<= 1) {
            int u = __shfl_up(t, off, 4);
            if (tid >= off) t += u;
        }
        wtot[tid] = t;
    }
    __syncthreads();
    if (wv > 0) inc += wtot[wv - 1];
    int excl = inc - c;
    cnt[tid] = excl;
    if (tid < nn) {
        rpe[n0 + tid] = make_int2(ebeg + excl, ebeg + inc);
    }
    __syncthreads();
    bool fits = sz <= CAPS;
    for (int i = tid; i < nq; i += 256) {
        uint4 p = bq[i];
        int d0 = (int)(p.x & 255u), d1 = (int)(p.y & 255u);
        int d2 = (int)(p.z & 255u), d3 = (int)(p.w & 255u);
        int p0 = cnt[d0] + atomicAdd(&cnt2[d0], 1);
        int p1 = cnt[d1] + atomicAdd(&cnt2[d1], 1);
        int p2 = cnt[d2] + atomicAdd(&cnt2[d2], 1);
        int p3 = cnt[d3] + atomicAdd(&cnt2[d3], 1);
        if (fits) {
            stage[p0] = (int)(p.x >> 8); stage[p1] = (int)(p.y >> 8);
            stage[p2] = (int)(p.z >> 8); stage[p3] = (int)(p.w >> 8);
        } else {
            col[ebeg + p0] = (int)(p.x >> 8); col[ebeg + p1] = (int)(p.y >> 8);
            col[ebeg + p2] = (int)(p.z >> 8); col[ebeg + p3] = (int)(p.w >> 8);
        }
    }
    for (int e = (nq << 2) + tid; e < sz; e += 256) {
        uint32 p = bpack[ebeg + e];
        int dl = (int)(p & 255u);
        int pos = cnt[dl] + atomicAdd(&cnt2[dl], 1);
        if (fits) stage[pos] = (int)(p >> 8);
        else col[ebeg + pos] = (int)(p >> 8);
    }
    __syncthreads();
    if (fits) {
        uint4* colq = (uint4*)(col + ebeg);
        const uint4* stq = (const uint4*)stage;
        for (int i = tid; i < nq; i += 256) colq[i] = stq[i];
        for (int i = (nq << 2) + tid; i < sz; i += 256) col[ebeg + i] = stage[i];
    }
}

// ---------------- nodes 4/5: fused agg(layer l) -> LDS -> gemm(W_{l+1}) ----------------
// Block owns rows [64b, 64b+64). Agg: 2 passes of (4 waves x 8 nodes x 8 heads).
// Activations live in Xs (f32, pad 68); gemm K=64 reads Xs/Ws directly.

__global__ __launch_bounds__(256) void layer_kernel(
    const unsigned short* __restrict__ Hin, const float* __restrict__ ALsIn,
    const float* __restrict__ ALdIn, const int2* __restrict__ rpe,
    const int* __restrict__ col, const float* __restrict__ biasIn,
    const float* __restrict__ Wn, const float* __restrict__ ansrc,
    const float* __restrict__ andst, unsigned short* __restrict__ Hout,
    float* __restrict__ ALsOut, float* __restrict__ ALdOut, int n) {
    const int KP = 68;
    __shared__ float Xs[64 * KP];
    __shared__ float Ws[64 * 64];
    int tid = threadIdx.x;
    int r0 = blockIdx.x * 64;
    int validRows = min(64, n - r0);

    {
        const float4* Wg = (const float4*)Wn;
        float4* Ws4 = (float4*)Ws;
        for (int i = tid; i < 64 * 16; i += 256) Ws4[i] = Wg[i];
    }
    if (validRows < 64) {   // tail block: zero pad rows before agg writes
        for (int i = tid; i < 64 * KP; i += 256) Xs[i] = 0.f;
        __syncthreads();
    }

    int lane = tid & 63, wv = tid >> 6;
    int slot = lane >> 3, head = lane & 7;
    const uint4* Hq = (const uint4*)Hin;
#pragma unroll
    for (int pass = 0; pass < 2; ++pass) {
        int row = pass * 32 + wv * 8 + slot;
        int d = r0 + row;
        if (d < n)
            agg_node(Hq, ALsIn, ALdIn, rpe, col, biasIn, d, head, &Xs[row * KP + head * 8]);
    }
    __syncthreads();

    // gemm K=64 from LDS
    int cg = tid & 15, rg = tid >> 4;
    int rbase = rg * 4;
    float4 acc0 = make_float4(0.f, 0.f, 0.f, 0.f);
    float4 acc1 = acc0, acc2 = acc0, acc3 = acc0;
#pragma unroll 2
    for (int k = 0; k < 64; k += 4) {
        float4 x0 = *(const float4*)&Xs[(rbase + 0) * KP + k];
        float4 x1 = *(const float4*)&Xs[(rbase + 1) * KP + k];
        float4 x2 = *(const float4*)&Xs[(rbase + 2) * KP + k];
        float4 x3 = *(const float4*)&Xs[(rbase + 3) * KP + k];
        float4 w0 = *(const float4*)&Ws[(k + 0) * 64 + 4 * cg];
        float4 w1 = *(const float4*)&Ws[(k + 1) * 64 + 4 * cg];
        float4 w2 = *(const float4*)&Ws[(k + 2) * 64 + 4 * cg];
        float4 w3 = *(const float4*)&Ws[(k + 3) * 64 + 4 * cg];
#define FMA4(A, S, WV) \
        A.x = fmaf(S, WV.x, A.x); A.y = fmaf(S, WV.y, A.y); \
        A.z = fmaf(S, WV.z, A.z); A.w = fmaf(S, WV.w, A.w)
        FMA4(acc0, x0.x, w0); FMA4(acc1, x1.x, w0); FMA4(acc2, x2.x, w0); FMA4(acc3, x3.x, w0);
        FMA4(acc0, x0.y, w1); FMA4(acc1, x1.y, w1); FMA4(acc2, x2.y, w1); FMA4(acc3, x3.y, w1);
        FMA4(acc0, x0.z, w2); FMA4(acc1, x1.z, w2); FMA4(acc2, x2.z, w2); FMA4(acc3, x3.z, w2);
        FMA4(acc0, x0.w, w3); FMA4(acc1, x1.w, w3); FMA4(acc2, x2.w, w3); FMA4(acc3, x3.w, w3);
#undef FMA4
    }

    int hh = cg >> 1;
    float4 as4 = ((const float4*)ansrc)[cg];
    float4 ad4 = ((const float4*)andst)[cg];
    float4 accs[4] = {acc0, acc1, acc2, acc3};
#pragma unroll
    for (int i = 0; i < 4; ++i) {
        int r = r0 + rbase + i;
        if (r < n) {
            ushort4 p;
            p.x = f2bf(accs[i].x); p.y = f2bf(accs[i].y);
            p.z = f2bf(accs[i].z); p.w = f2bf(accs[i].w);
            ((ushort4*)Hout)[(size_t)r * 16 + cg] = p;
            float ps = accs[i].x * as4.x + accs[i].y * as4.y +
                       accs[i].z * as4.z + accs[i].w * as4.w;
            float pd = accs[i].x * ad4.x + accs[i].y * ad4.y +
                       accs[i].z * ad4.z + accs[i].w * ad4.w;
            ps += __shfl_xor(ps, 1);
            pd += __shfl_xor(pd, 1);
            if ((cg & 1) == 0) {
                ALsOut[r * 8 + hh] = ps;
                ALdOut[r * 8 + hh] = pd;
            }
        }
    }
}

// ---------------- node 6: agg(layer 3) -> pool partials -> ticket -> final ----------------

__global__ __launch_bounds__(256) void last_kernel(
    const unsigned short* __restrict__ Hin, const float* __restrict__ ALsIn,
    const float* __restrict__ ALdIn, const int2* __restrict__ rpe,
    const int* __restrict__ col, const float* __restrict__ biasIn,
    const int* __restrict__ batch, float* __restrict__ sums,
    float* __restrict__ gcnt, int* __restrict__ ticket,
    const float* __restrict__ linW, const float* __restrict__ linb,
    float* __restrict__ out, int n) {
    const int KP = 68;
    __shared__ float Xs[64 * KP];
    __shared__ int lflag;
    int tid = threadIdx.x;
    int r0 = blockIdx.x * 64;
    int validRows = min(64, n - r0);

    if (validRows < 64) {
        for (int i = tid; i < 64 * KP; i += 256) Xs[i] = 0.f;
        __syncthreads();
    }

    int lane = tid & 63, wv = tid >> 6;
    int slot = lane >> 3, head = lane & 7;
    const uint4* Hq = (const uint4*)Hin;
#pragma unroll
    for (int pass = 0; pass < 2; ++pass) {
        int row = pass * 32 + wv * 8 + slot;
        int d = r0 + row;
        if (d < n)
            agg_node(Hq, ALsIn, ALdIn, rpe, col, biasIn, d, head, &Xs[row * KP + head * 8]);
    }
    __syncthreads();

    // pool: 4 row-groups of 16, 64 feature lanes each
    int f = tid & 63, q = tid >> 6;
    int rbeg = q * 16, rend = min(rbeg + 16, validRows);
    if (rbeg < rend) {
        int curb = batch[r0 + rbeg];
        float loc = 0.f, c = 0.f;
        for (int row = rbeg; row < rend; ++row) {
            int b = batch[r0 + row];
            if (b != curb) {
                atomicAdd(&sums[curb * 64 + f], loc);
                if (f == 0) atomicAdd(&gcnt[curb], c);
                loc = 0.f; c = 0.f; curb = b;
            }
            loc += Xs[row * KP + f];
            c += 1.f;
        }
        atomicAdd(&sums[curb * 64 + f], loc);
        if (f == 0) atomicAdd(&gcnt[curb], c);
    }

    __threadfence();
    __syncthreads();
    if (tid == 0) {
        int t = __hip_atomic_fetch_add(ticket, 1, __ATOMIC_ACQ_REL, __HIP_MEMORY_SCOPE_AGENT);
        lflag = (t == (int)gridDim.x - 1) ? 1 : 0;
    }
    __syncthreads();
    if (lflag) {
        for (int t2 = tid; t2 < GG * NCLS; t2 += 256) {
            int g = t2 / NCLS, k = t2 % NCLS;
            float c = __hip_atomic_load(&gcnt[g], __ATOMIC_RELAXED, __HIP_MEMORY_SCOPE_AGENT);
            if (c < 1.f) c = 1.f;
            float inv = 1.f / c;
            float acc = linb[k];
#pragma unroll
            for (int cc = 0; cc < 64; ++cc) {
                float s = __hip_atomic_load(&sums[g * 64 + cc], __ATOMIC_RELAXED,
                                            __HIP_MEMORY_SCOPE_AGENT);
                acc = fmaf(s * inv, linW[cc * NCLS + k], acc);
            }
            out[t2] = acc;
        }
    }
}

// ---------------- launch ----------------

extern "C" void kernel_launch(void* const* d_in, const int* in_sizes, int n_in,
                              void* d_out, int out_size, void* d_ws, size_t ws_size,
                              hipStream_t stream) {
    const float* x    = (const float*)d_in[0];
    const int*   ei   = (const int*)d_in[1];   // [2,E]: src = ei, dst = ei+EE
    const int*   batch = (const int*)d_in[2];
    const float* W1 = (const float*)d_in[3];
    const float* a1s = (const float*)d_in[4];
    const float* a1d = (const float*)d_in[5];
    const float* b1 = (const float*)d_in[6];
    const float* W2 = (const float*)d_in[7];
    const float* a2s = (const float*)d_in[8];
    const float* a2d = (const float*)d_in[9];
    const float* b2 = (const float*)d_in[10];
    const float* W3 = (const float*)d_in[11];
    const float* a3s = (const float*)d_in[12];
    const float* a3d = (const float*)d_in[13];
    const float* b3 = (const float*)d_in[14];
    const float* linW = (const float*)d_in[15];
    const float* linb = (const float*)d_in[16];
    float* out = (float*)d_out;

    char* ws = (char*)d_ws;
    size_t off = 0;
    auto alloc = [&](size_t bytes) -> void* {
        void* p = ws + off;
        off = (off + bytes + 255) & ~(size_t)255;
        return p;
    };
    // contiguous zero-region: bfill | sums | gcnt | ticket  (one memset per replay)
    const size_t ZBYTES = (size_t)NB * 4 + (size_t)GG * 64 * 4 + (size_t)GG * 4 + 4;
    char* zr = (char*)alloc(ZBYTES);
    int*   bfill = (int*)zr;
    float* sums  = (float*)(zr + (size_t)NB * 4);
    float* gcnt  = sums + GG * 64;
    int*   ticket = (int*)(gcnt + GG);

    unsigned short* hA = (unsigned short*)alloc((size_t)NN * 64 * 2);
    unsigned short* hB = (unsigned short*)alloc((size_t)NN * 64 * 2);
    float* ALsA = (float*)alloc((size_t)NN * 8 * 4);
    float* ALdA = (float*)alloc((size_t)NN * 8 * 4);
    float* ALsB = (float*)alloc((size_t)NN * 8 * 4);
    float* ALdB = (float*)alloc((size_t)NN * 8 * 4);
    int2*  rpe  = (int2*)alloc((size_t)NN * 8);
    uint32* bpack = (uint32*)alloc((size_t)NB * BCAP * 4);
    int*   col  = (int*)alloc((size_t)NB * BCAP * 4);

    hipMemsetAsync(zr, 0, ZBYTES, stream);

    // node 2: bscatter || gemm1
    pre_kernel<<<SBLK + GB, 512, 0, stream>>>(ei, ei + EE, bfill, bpack, EE,
                                              x, W1, a1s, a1d, hA, ALsA, ALdA);
    // node 3: CSR finalize
    bsort_kernel<<<NB, 256, 0, stream>>>(bpack, bfill, rpe, col);

    // node 4: agg(L1) -> gemm(W2)
    layer_kernel<<<GB, 256, 0, stream>>>(hA, ALsA, ALdA, rpe, col, b1,
                                         W2, a2s, a2d, hB, ALsB, ALdB, NN);
    // node 5: agg(L2) -> gemm(W3)
    layer_kernel<<<GB, 256, 0, stream>>>(hB, ALsB, ALdB, rpe, col, b2,
                                         W3, a3s, a3d, hA, ALsA, ALdA, NN);
    // node 6: agg(L3) -> pool -> final
    last_kernel<<<GB, 256, 0, stream>>>(hA, ALsA, ALdA, rpe, col, b3,
                                        batch, sums, gcnt, ticket, linW, linb, out, NN);
}